// Round 17
// baseline (80.492 us; speedup 1.0000x reference)
//
#include <hip/hip_runtime.h>
#include <math.h>

typedef unsigned short u16;
typedef __attribute__((ext_vector_type(4))) float f32x4;
typedef __attribute__((ext_vector_type(8))) short s16x8;   // MFMA bf16 frag (8 bf16)
typedef __attribute__((ext_vector_type(4))) unsigned short u16x4;
typedef __attribute__((ext_vector_type(8))) unsigned short u16x8;

__device__ __forceinline__ u16 f2b(float f) {
  union { float f; unsigned u; } v; v.f = f;
  return (u16)((v.u + 0x7fffu + ((v.u >> 16) & 1u)) >> 16);
}
__device__ __forceinline__ float b2f(u16 b) {
  union { unsigned u; float f; } v; v.u = ((unsigned)b) << 16;
  return v.f;
}

// ---------------------------------------------------------------------------
// 128x128-tile bf16 MFMA GEMM with cast-in-staging (A,B sources are f32):
// y<8  -> cqkv = emb@qkv^T (1024x6144)
// y==8 -> pqkv = pe@qkv^T (128x6144); pe computed IN-REGISTER (sin/cos)
// y==9 -> fc_w f32 -> fcx bf16 cast only (48 blocks, strided)
// ---------------------------------------------------------------------------
__global__ __launch_bounds__(256) void gemm128(
    const float* __restrict__ embf, const float* __restrict__ qkvf,
    const float* __restrict__ fcf,
    u16* __restrict__ Ccq, u16* __restrict__ Cpq, u16* __restrict__ fcx)
{
  const int ytile = blockIdx.y;
  const int tid = threadIdx.x;
  if (ytile == 9) {
    for (int q = blockIdx.x * 256 + tid; q < 131072; q += 48 * 256) {
      const int off4 = q * 4;
      const int row = off4 >> 11, col = off4 & 2047;
      f32x4 v = *(const f32x4*)&fcf[(size_t)off4];
      u16x4 o = { f2b(v[0]), f2b(v[1]), f2b(v[2]), f2b(v[3]) };
      *(u16x4*)&fcx[(size_t)row * 2560 + col] = o;
    }
    return;
  }
  __shared__ __align__(16) u16 As[128 * 64];
  __shared__ __align__(16) u16 Bs[128 * 64];
  u16* C; int m0;
  const bool peA = (ytile == 8);
  if (peA) { C = Cpq; m0 = 0; }
  else     { C = Ccq; m0 = ytile * 128; }
  const int n0 = blockIdx.x * 128;
  const int w = tid >> 6, l = tid & 63, hi = l >> 4, lo = l & 15;
  const int wr = (w >> 1) * 64, wc = (w & 1) * 64;
  const int srow = tid >> 3, scol = (tid & 7) * 8;
  f32x4 acc[4][4] = {};
  for (int k0 = 0; k0 < 256; k0 += 64) {
    __syncthreads();
    #pragma unroll
    for (int q = 0; q < 4; ++q) {
      const int row = q * 32 + srow;
      const int sidx = row * 64 + (scol ^ ((row & 7) << 3));
      if (peA) {
        u16x8 oa = {0, 0, 0, 0, 0, 0, 0, 0};
        if (row < 64) {
          #pragma unroll
          for (int d2 = 0; d2 < 4; ++d2) {
            const int kf = ((k0 + scol) >> 1) + d2;
            const float fr = __expf(-(float)kf * 0.07195578415606394f);
            const float ph = (float)row * fr;
            float s, c;
            __sincosf(ph, &s, &c);
            oa[d2 * 2]     = f2b(s);
            oa[d2 * 2 + 1] = f2b(c);
          }
        }
        *(u16x8*)&As[sidx] = oa;
      } else {
        f32x4 a0 = *(const f32x4*)&embf[(long)(m0 + row) * 256 + k0 + scol];
        f32x4 a1 = *(const f32x4*)&embf[(long)(m0 + row) * 256 + k0 + scol + 4];
        u16x8 oa = { f2b(a0[0]), f2b(a0[1]), f2b(a0[2]), f2b(a0[3]),
                     f2b(a1[0]), f2b(a1[1]), f2b(a1[2]), f2b(a1[3]) };
        *(u16x8*)&As[sidx] = oa;
      }
      f32x4 b0 = *(const f32x4*)&qkvf[(long)(n0 + row) * 256 + k0 + scol];
      f32x4 b1 = *(const f32x4*)&qkvf[(long)(n0 + row) * 256 + k0 + scol + 4];
      u16x8 ob = { f2b(b0[0]), f2b(b0[1]), f2b(b0[2]), f2b(b0[3]),
                   f2b(b1[0]), f2b(b1[1]), f2b(b1[2]), f2b(b1[3]) };
      *(u16x8*)&Bs[sidx] = ob;
    }
    __syncthreads();
    #pragma unroll
    for (int kk = 0; kk < 2; ++kk) {
      s16x8 a[4], bf[4];
      #pragma unroll
      for (int m = 0; m < 4; ++m) {
        const int ar = wr + m * 16 + lo;
        a[m] = *(const s16x8*)&As[ar * 64 + ((hi * 8 + kk * 32) ^ ((ar & 7) << 3))];
      }
      #pragma unroll
      for (int n = 0; n < 4; ++n) {
        const int br = wc + n * 16 + lo;
        bf[n] = *(const s16x8*)&Bs[br * 64 + ((hi * 8 + kk * 32) ^ ((br & 7) << 3))];
      }
      #pragma unroll
      for (int m = 0; m < 4; ++m)
        #pragma unroll
        for (int n = 0; n < 4; ++n)
          acc[m][n] = __builtin_amdgcn_mfma_f32_16x16x32_bf16(a[m], bf[n], acc[m][n], 0, 0, 0);
    }
  }
  #pragma unroll
  for (int m = 0; m < 4; ++m)
    #pragma unroll
    for (int n = 0; n < 4; ++n)
      #pragma unroll
      for (int r = 0; r < 4; ++r)
        C[(long)(m0 + wr + m * 16 + hi * 4 + r) * 6144 + n0 + wc + n * 16 + lo] = f2b(acc[m][n][r]);
}

// ---------------------------------------------------------------------------
// 64x64-tile bf16 MFMA GEMM (batched, f32 out) — fc split-K x8.
// ---------------------------------------------------------------------------
__global__ __launch_bounds__(256) void gemm_bf(
    const u16* __restrict__ A, int lda, long sA,
    const u16* __restrict__ B, int ldb, long sB,
    float* __restrict__ C, int ldc, long sC, int K)
{
  __shared__ __align__(16) u16 As[64 * 64];
  __shared__ __align__(16) u16 Bs[64 * 64];
  const int z = blockIdx.z;
  A += (long)z * sA;  B += (long)z * sB;
  const int m0 = blockIdx.y * 64, n0 = blockIdx.x * 64;
  const int tid = threadIdx.x;
  const int r8 = tid >> 3, s8t = (tid & 7) * 8;
  const int w = tid >> 6, l = tid & 63, hi = l >> 4, lo = l & 15;
  f32x4 acc[4] = {};
  for (int k0 = 0; k0 < K; k0 += 64) {
    __syncthreads();
    #pragma unroll
    for (int q = 0; q < 2; ++q) {
      const int row = q * 32 + r8;
      const int sidx = row * 64 + (s8t ^ ((row & 7) << 3));
      *(u16x8*)&As[sidx] = *(const u16x8*)&A[(long)(m0 + row) * lda + k0 + s8t];
      *(u16x8*)&Bs[sidx] = *(const u16x8*)&B[(long)(n0 + row) * ldb + k0 + s8t];
    }
    __syncthreads();
    #pragma unroll
    for (int kk = 0; kk < 2; ++kk) {
      const int arow = w * 16 + lo;
      s16x8 a = *(const s16x8*)&As[arow * 64 + ((hi * 8 + kk * 32) ^ ((arow & 7) << 3))];
      #pragma unroll
      for (int n = 0; n < 4; ++n) {
        const int brow = n * 16 + lo;
        s16x8 bfr = *(const s16x8*)&Bs[brow * 64 + ((hi * 8 + kk * 32) ^ ((brow & 7) << 3))];
        acc[n] = __builtin_amdgcn_mfma_f32_16x16x32_bf16(a, bfr, acc[n], 0, 0, 0);
      }
    }
  }
  const long zoff = (long)z * sC;
  #pragma unroll
  for (int n = 0; n < 4; ++n)
    #pragma unroll
    for (int r = 0; r < 4; ++r)
      C[zoff + (long)(m0 + w * 16 + hi * 4 + r) * ldc + n0 + n * 16 + lo] = acc[n][r];
}

// ---------------------------------------------------------------------------
// tables_kernel: merged cpqk (dual GEMM, blocks 0..127) + pqk (128..135) +
// pvfc (136..167). All 64x64 tiles, K=256, bf16 out.
// ---------------------------------------------------------------------------
__global__ __launch_bounds__(256) void tables_kernel(
    const u16* __restrict__ cqkv, const u16* __restrict__ pqkv,
    const u16* __restrict__ fcx,
    u16* __restrict__ cpqk, u16* __restrict__ pqk, u16* __restrict__ pvfc)
{
  __shared__ __align__(16) u16 As1[64 * 64], Bs1[64 * 64];
  __shared__ __align__(16) u16 As2[64 * 64], Bs2[64 * 64];
  const int blk = blockIdx.x;
  const u16 *A1, *A2 = nullptr, *B1, *B2 = nullptr;
  u16* C; int lda, ldb, ldc, m0; bool dual = false;
  if (blk < 128) {
    const int h = blk & 7, mt = blk >> 3;
    A1 = cqkv + h * 768 + 256; A2 = cqkv + h * 768;
    B1 = pqkv + h * 768;       B2 = pqkv + h * 768 + 256;
    lda = 6144; ldb = 6144; C = cpqk + (long)h * 65536; ldc = 64;
    m0 = mt * 64; dual = true;
  } else if (blk < 136) {
    const int h = blk - 128;
    A1 = pqkv + h * 768; B1 = pqkv + h * 768 + 256;
    lda = 6144; ldb = 6144; C = pqk + h * 4096; ldc = 64; m0 = 0;
  } else {
    const int idx = blk - 136, h = idx & 7, mt = idx >> 3;
    A1 = fcx + h * 256; B1 = pqkv + 512 + h * 768;
    lda = 2560; ldb = 6144; C = pvfc + h * 64; ldc = 2560; m0 = mt * 64;
  }
  const int tid = threadIdx.x;
  const int r8 = tid >> 3, s8t = (tid & 7) * 8;
  const int w = tid >> 6, l = tid & 63, hi = l >> 4, lo = l & 15;
  f32x4 acc[4] = {};
  for (int k0 = 0; k0 < 256; k0 += 64) {
    __syncthreads();
    #pragma unroll
    for (int q = 0; q < 2; ++q) {
      const int row = q * 32 + r8;
      const int sidx = row * 64 + (s8t ^ ((row & 7) << 3));
      *(u16x8*)&As1[sidx] = *(const u16x8*)&A1[(long)(m0 + row) * lda + k0 + s8t];
      *(u16x8*)&Bs1[sidx] = *(const u16x8*)&B1[(long)row * ldb + k0 + s8t];
      if (dual) {
        *(u16x8*)&As2[sidx] = *(const u16x8*)&A2[(long)(m0 + row) * lda + k0 + s8t];
        *(u16x8*)&Bs2[sidx] = *(const u16x8*)&B2[(long)row * ldb + k0 + s8t];
      }
    }
    __syncthreads();
    #pragma unroll
    for (int kk = 0; kk < 2; ++kk) {
      const int arow = w * 16 + lo;
      const int aidx = arow * 64 + ((hi * 8 + kk * 32) ^ ((arow & 7) << 3));
      s16x8 a1 = *(const s16x8*)&As1[aidx];
      #pragma unroll
      for (int n = 0; n < 4; ++n) {
        const int brow = n * 16 + lo;
        const int bidx = brow * 64 + ((hi * 8 + kk * 32) ^ ((brow & 7) << 3));
        acc[n] = __builtin_amdgcn_mfma_f32_16x16x32_bf16(a1, *(const s16x8*)&Bs1[bidx], acc[n], 0, 0, 0);
      }
      if (dual) {
        s16x8 a2 = *(const s16x8*)&As2[aidx];
        #pragma unroll
        for (int n = 0; n < 4; ++n) {
          const int brow = n * 16 + lo;
          const int bidx = brow * 64 + ((hi * 8 + kk * 32) ^ ((brow & 7) << 3));
          acc[n] = __builtin_amdgcn_mfma_f32_16x16x32_bf16(a2, *(const s16x8*)&Bs2[bidx], acc[n], 0, 0, 0);
        }
      }
    }
  }
  #pragma unroll
  for (int n = 0; n < 4; ++n)
    #pragma unroll
    for (int r = 0; r < 4; ++r)
      C[(long)(m0 + w * 16 + hi * 4 + r) * ldc + n * 16 + lo] = f2b(acc[n][r]);
}

// ---------------------------------------------------------------------------
// Attention per (h,b). blockIdx.x = h -> XCD affinity. 4 blocks/CU.
// R16 structure + f32 table LDS (no bf16 re-encode) + setprio around MFMA.
// ---------------------------------------------------------------------------
__global__ __launch_bounds__(256, 4) void attn_kernel(
    const int* __restrict__ cc, const u16* __restrict__ cqkv,
    const u16* __restrict__ cpqk, const u16* __restrict__ pqk,
    u16* __restrict__ outp)
{
  __shared__ __align__(16) u16 Ks[64 * 256];   // 32 KB: K -> f32 tables -> V -> pf
  __shared__ float poolp[4][64];
  __shared__ float pooled[64];
  const int h = blockIdx.x, b = blockIdx.y;
  const int tid = threadIdx.x;
  const long hq = (long)h * 768;

  const int w = tid >> 6, l = tid & 63, hi = l >> 4, lo = l & 15;
  const int r8 = tid >> 3, s8t = (tid & 7) * 8;
  const int rb = r8 + 32;
  const int swa = (r8 & 7) << 3, swb = (rb & 7) << 3;

  const int cl = cc[b * 64 + l];
  const float invn = 1.f / (float)__popcll(__ballot(cl != 0));

  const int ca = __shfl(cl, r8), cb2 = __shfl(cl, rb);
  const long rowa = (long)ca * 6144 + hq;
  const long rowb = (long)cb2 * 6144 + hq;

  // ---- all global loads issue here (128B/line per instr) ----
  u16x8 kr[8];
  #pragma unroll
  for (int p = 0; p < 4; ++p) {
    kr[p]     = *(const u16x8*)&cqkv[rowa + 256 + p * 64 + s8t];
    kr[p + 4] = *(const u16x8*)&cqkv[rowb + 256 + p * 64 + s8t];
  }
  u16x8 vr[8];
  #pragma unroll
  for (int p = 0; p < 4; ++p) {
    vr[p]     = *(const u16x8*)&cqkv[rowa + 512 + p * 64 + s8t];
    vr[p + 4] = *(const u16x8*)&cqkv[rowb + 512 + p * 64 + s8t];
  }
  u16x8 cta = *(const u16x8*)&cpqk[((long)h * 1024 + ca) * 64 + s8t];
  u16x8 ctb = *(const u16x8*)&cpqk[((long)h * 1024 + cb2) * 64 + s8t];
  u16x8 pta = *(const u16x8*)&pqk[(long)h * 4096 + (long)r8 * 64 + s8t];
  u16x8 ptb = *(const u16x8*)&pqk[(long)h * 4096 + (long)rb * 64 + s8t];
  const long qrow = (long)__shfl(cl, w * 16 + lo) * 6144 + hq;
  s16x8 a[8];
  #pragma unroll
  for (int kk = 0; kk < 8; ++kk)
    a[kk] = *(const s16x8*)&cqkv[qrow + kk * 32 + hi * 8];

  // ---- stage K into Ks (XOR-swizzled) ----
  #pragma unroll
  for (int p = 0; p < 4; ++p) {
    *(u16x8*)&Ks[r8 * 256 + ((p * 64 + s8t) ^ swa)] = kr[p];
    *(u16x8*)&Ks[rb * 256 + ((p * 64 + s8t) ^ swb)] = kr[p + 4];
  }
  __syncthreads();

  // ---- QK^T MFMA (prioritized: 4 independent blocks/CU arbitrate) ----
  __builtin_amdgcn_s_setprio(1);
  f32x4 acc[4] = {};
  #pragma unroll
  for (int kk = 0; kk < 8; ++kk) {
    #pragma unroll
    for (int n = 0; n < 4; ++n) {
      const int brow = n * 16 + lo;
      s16x8 bfr = *(const s16x8*)&Ks[brow * 256 + ((hi * 8 + kk * 32) ^ ((brow & 7) << 3))];
      acc[n] = __builtin_amdgcn_mfma_f32_16x16x32_bf16(a[kk], bfr, acc[n], 0, 0, 0);
    }
  }
  __builtin_amdgcn_s_setprio(0);
  __syncthreads();   // K dead

  // ---- f32 summed tables -> Ks bytes [0,16384) ----
  float* tf = (float*)Ks;   // [64][64] f32
  {
    const int ta = r8 * 64 + (s8t ^ swa);
    const int tb = rb * 64 + (s8t ^ swb);
    f32x4 a0 = { b2f(cta[0]) + b2f(pta[0]), b2f(cta[1]) + b2f(pta[1]),
                 b2f(cta[2]) + b2f(pta[2]), b2f(cta[3]) + b2f(pta[3]) };
    f32x4 a1 = { b2f(cta[4]) + b2f(pta[4]), b2f(cta[5]) + b2f(pta[5]),
                 b2f(cta[6]) + b2f(pta[6]), b2f(cta[7]) + b2f(pta[7]) };
    f32x4 b0 = { b2f(ctb[0]) + b2f(ptb[0]), b2f(ctb[1]) + b2f(ptb[1]),
                 b2f(ctb[2]) + b2f(ptb[2]), b2f(ctb[3]) + b2f(ptb[3]) };
    f32x4 b1 = { b2f(ctb[4]) + b2f(ptb[4]), b2f(ctb[5]) + b2f(ptb[5]),
                 b2f(ctb[6]) + b2f(ptb[6]), b2f(ctb[7]) + b2f(ptb[7]) };
    *(f32x4*)&tf[ta]     = a0;
    *(f32x4*)&tf[ta + 4] = a1;
    *(f32x4*)&tf[tb]     = b0;
    *(f32x4*)&tf[tb + 4] = b1;
  }
  __syncthreads();

  // ---- softmax (f32 tables from LDS; cs via shfl) ----
  const float scale = 0.0625f;
  int csj[4];
  #pragma unroll
  for (int n = 0; n < 4; ++n) csj[n] = __shfl(cl, n * 16 + lo);
  float ex[4][4];
  float wgt[4];
  #pragma unroll
  for (int r = 0; r < 4; ++r) {
    const int i = w * 16 + hi * 4 + r;
    const int tswz = (i & 7) << 3;
    float s[4];
    float mx = -3e38f;
    #pragma unroll
    for (int n = 0; n < 4; ++n) {
      const int j = n * 16 + lo;
      float v = (acc[n][r] + tf[i * 64 + (j ^ tswz)]) * scale;
      if (csj[n] == 0) v = -1e9f;
      s[n] = v;
      mx = fmaxf(mx, v);
    }
    mx = fmaxf(mx, __shfl_xor(mx, 1));
    mx = fmaxf(mx, __shfl_xor(mx, 2));
    mx = fmaxf(mx, __shfl_xor(mx, 4));
    mx = fmaxf(mx, __shfl_xor(mx, 8));
    float sum = 0.f;
    #pragma unroll
    for (int n = 0; n < 4; ++n) { const float e = __expf(s[n] - mx); ex[n][r] = e; sum += e; }
    sum += __shfl_xor(sum, 1);
    sum += __shfl_xor(sum, 2);
    sum += __shfl_xor(sum, 4);
    sum += __shfl_xor(sum, 8);
    wgt[r] = (__shfl(cl, i) != 0 ? 1.f : 0.f) / sum;
  }
  #pragma unroll
  for (int n = 0; n < 4; ++n) {
    float cp = ex[n][0] * wgt[0] + ex[n][1] * wgt[1] + ex[n][2] * wgt[2] + ex[n][3] * wgt[3];
    cp += __shfl_xor(cp, 16);
    cp += __shfl_xor(cp, 32);
    if (hi == 0) poolp[w][n * 16 + lo] = cp;
  }
  __syncthreads();   // poolp ready; all table reads done -> Ks free

  // ---- pooled final (separate LDS) + raw cv staging ----
  if (tid < 64) {
    const float pl = (poolp[0][tid] + poolp[1][tid] + poolp[2][tid] + poolp[3][tid]) * invn;
    pooled[tid] = pl;
    outp[(long)b * 2560 + 2048 + h * 64 + tid] = f2b(pl);
  }
  #pragma unroll
  for (int p = 0; p < 4; ++p) {
    *(u16x8*)&Ks[r8 * 256 + ((p * 64 + s8t) ^ swa)] = vr[p];
    *(u16x8*)&Ks[rb * 256 + ((p * 64 + s8t) ^ swb)] = vr[p + 4];
  }
  __syncthreads();

  // ---- PV: blocked column-sum with pooled FMA ----
  const int g = tid >> 5, ch = tid & 31;
  float acc8[8] = {};
  #pragma unroll
  for (int jj = 0; jj < 8; ++jj) {
    const int j = g * 8 + jj;
    const float pj = pooled[j];
    u16x8 vv = *(const u16x8*)&Ks[j * 256 + ((ch * 8) ^ ((j & 7) << 3))];
    #pragma unroll
    for (int d = 0; d < 8; ++d) acc8[d] += pj * b2f(vv[d]);
  }
  #pragma unroll
  for (int d = 0; d < 8; ++d) acc8[d] += __shfl_xor(acc8[d], 32);
  __syncthreads();   // all V reads complete; Ks free for partials
  float* pfF = (float*)Ks;   // [4][256] f32 = 4 KB
  if (l < 32) {
    f32x4 lo4 = { acc8[0], acc8[1], acc8[2], acc8[3] };
    f32x4 hi4 = { acc8[4], acc8[5], acc8[6], acc8[7] };
    *(f32x4*)&pfF[w * 256 + ch * 8]     = lo4;
    *(f32x4*)&pfF[w * 256 + ch * 8 + 4] = hi4;
  }
  __syncthreads();
  const float o = pfF[tid] + pfF[256 + tid] + pfF[512 + tid] + pfF[768 + tid];
  outp[(long)b * 2560 + h * 256 + tid] = f2b(o);
}

// ---------------------------------------------------------------------------
// LN chain; input = 8 split-K partials of fc output + bias
// ---------------------------------------------------------------------------
__global__ __launch_bounds__(256) void ln_chain(
    const float* __restrict__ xp, const float* __restrict__ fcb,
    const float* __restrict__ g1, const float* __restrict__ b1,
    const float* __restrict__ g2, const float* __restrict__ b2,
    const float* __restrict__ g3, const float* __restrict__ b3,
    float* __restrict__ out)
{
  __shared__ float red[4];
  const int b = blockIdx.x, t = threadIdx.x;
  const long idx = (long)b * 256 + t;
  float v = fcb[t];
  #pragma unroll
  for (int z = 0; z < 8; ++z) v += xp[idx + (long)z * 131072];

  auto bsum = [&](float val) -> float {
    #pragma unroll
    for (int o = 32; o; o >>= 1) val += __shfl_down(val, o);
    __syncthreads();
    if ((t & 63) == 0) red[t >> 6] = val;
    __syncthreads();
    return red[0] + red[1] + red[2] + red[3];
  };

  float mean = bsum(v) * (1.f / 256.f);
  float d = v - mean;
  float var = bsum(d * d) * (1.f / 256.f);
  const float y1 = d * rsqrtf(var + 1e-5f) * g1[t] + b1[t];

  mean = bsum(y1) * (1.f / 256.f);
  d = y1 - mean;
  var = bsum(d * d) * (1.f / 256.f);
  const float y2 = d * rsqrtf(var + 1e-6f) * g2[t] + b2[t] + y1;

  mean = bsum(y2) * (1.f / 256.f);
  d = y2 - mean;
  var = bsum(d * d) * (1.f / 256.f);
  out[idx] = d * rsqrtf(var + 1e-5f) * g3[t] + b3[t];
}

// ---------------------------------------------------------------------------
extern "C" void kernel_launch(void* const* d_in, const int* in_sizes, int n_in,
                              void* d_out, int out_size, void* d_ws, size_t ws_size,
                              hipStream_t stream) {
  (void)in_sizes; (void)n_in; (void)out_size; (void)ws_size;
  const int*   cc    = (const int*)  d_in[0];
  const float* emb_w = (const float*)d_in[1];   // (1024,256)
  const float* qkv_w = (const float*)d_in[2];   // (6144,256)
  const float* fc_w  = (const float*)d_in[3];   // (256,2048)
  const float* fc_b  = (const float*)d_in[4];
  const float* sg    = (const float*)d_in[5];
  const float* sb    = (const float*)d_in[6];
  const float* fg    = (const float*)d_in[7];
  const float* fb    = (const float*)d_in[8];
  const float* bg    = (const float*)d_in[9];
  const float* bbv   = (const float*)d_in[10];
  float* out = (float*)d_out;

  char* p = (char*)d_ws;
  u16* fcx     = (u16*)p;  p += (size_t)256 * 2560 * 2;    // [fc_w | pvfc]
  u16* cqkv_bf = (u16*)p;  p += (size_t)1024 * 6144 * 2;
  u16* pqkv_bf = (u16*)p;  p += (size_t)128 * 6144 * 2;    // rows 64..127 zero
  u16* cpqk16  = (u16*)p;  p += (size_t)8 * 1024 * 64 * 2;
  u16* pqk16   = (u16*)p;  p += (size_t)8 * 64 * 64 * 2;
  u16* sdpa_bf = (u16*)p;  p += (size_t)512 * 2560 * 2;    // [attn-out | pooled]
  float* fco   = (float*)p; p += (size_t)8 * 512 * 256 * 4;

  // cqkv (y<8) + pqkv w/ in-register pe (y==8) + fc cast (y==9)
  gemm128<<<dim3(48, 10), dim3(256), 0, stream>>>(
      emb_w, qkv_w, fc_w, cqkv_bf, pqkv_bf, fcx);

  // merged cpqk + pqk + pvfc
  tables_kernel<<<dim3(168), dim3(256), 0, stream>>>(
      cqkv_bf, pqkv_bf, fcx, cpqk16, pqk16, fcx + 2048);

  // attention: blockIdx.x = h (XCD affinity), y = b
  attn_kernel<<<dim3(8, 512), dim3(256), 0, stream>>>(
      cc, cqkv_bf, cpqk16, pqk16, sdpa_bf);

  // fc split-K x8 over K=2560
  gemm_bf<<<dim3(4, 8, 8), dim3(256), 0, stream>>>(
      sdpa_bf, 2560, 320, fcx, 2560, 320, fco, 256, (long)512 * 256, 320);

  ln_chain<<<dim3(512), dim3(256), 0, stream>>>(fco, fc_b, sg, sb, fg, fb, bg, bbv, out);
}

// Round 18
// 80.379 us; speedup vs baseline: 1.0014x; 1.0014x over previous
//
#include <hip/hip_runtime.h>
#include <math.h>

typedef unsigned short u16;
typedef __attribute__((ext_vector_type(4))) float f32x4;
typedef __attribute__((ext_vector_type(8))) short s16x8;   // MFMA bf16 frag (8 bf16)
typedef __attribute__((ext_vector_type(4))) unsigned short u16x4;
typedef __attribute__((ext_vector_type(8))) unsigned short u16x8;

__device__ __forceinline__ u16 f2b(float f) {
  union { float f; unsigned u; } v; v.f = f;
  return (u16)((v.u + 0x7fffu + ((v.u >> 16) & 1u)) >> 16);
}
__device__ __forceinline__ float b2f(u16 b) {
  union { unsigned u; float f; } v; v.u = ((unsigned)b) << 16;
  return v.f;
}

// ---------------------------------------------------------------------------
// 128x128-tile bf16 MFMA GEMM with cast-in-staging (A,B sources are f32):
// y<8  -> cqkv = emb@qkv^T (1024x6144)
// y==8 -> pqkv = pe@qkv^T (128x6144); pe computed IN-REGISTER (sin/cos)
// y==9 -> fc_w f32 -> fcx bf16 cast only (48 blocks, strided)
// ---------------------------------------------------------------------------
__global__ __launch_bounds__(256) void gemm128(
    const float* __restrict__ embf, const float* __restrict__ qkvf,
    const float* __restrict__ fcf,
    u16* __restrict__ Ccq, u16* __restrict__ Cpq, u16* __restrict__ fcx)
{
  const int ytile = blockIdx.y;
  const int tid = threadIdx.x;
  if (ytile == 9) {
    for (int q = blockIdx.x * 256 + tid; q < 131072; q += 48 * 256) {
      const int off4 = q * 4;
      const int row = off4 >> 11, col = off4 & 2047;
      f32x4 v = *(const f32x4*)&fcf[(size_t)off4];
      u16x4 o = { f2b(v[0]), f2b(v[1]), f2b(v[2]), f2b(v[3]) };
      *(u16x4*)&fcx[(size_t)row * 2560 + col] = o;
    }
    return;
  }
  __shared__ __align__(16) u16 As[128 * 64];
  __shared__ __align__(16) u16 Bs[128 * 64];
  u16* C; int m0;
  const bool peA = (ytile == 8);
  if (peA) { C = Cpq; m0 = 0; }
  else     { C = Ccq; m0 = ytile * 128; }
  const int n0 = blockIdx.x * 128;
  const int w = tid >> 6, l = tid & 63, hi = l >> 4, lo = l & 15;
  const int wr = (w >> 1) * 64, wc = (w & 1) * 64;
  const int srow = tid >> 3, scol = (tid & 7) * 8;
  f32x4 acc[4][4] = {};
  for (int k0 = 0; k0 < 256; k0 += 64) {
    __syncthreads();
    #pragma unroll
    for (int q = 0; q < 4; ++q) {
      const int row = q * 32 + srow;
      const int sidx = row * 64 + (scol ^ ((row & 7) << 3));
      if (peA) {
        u16x8 oa = {0, 0, 0, 0, 0, 0, 0, 0};
        if (row < 64) {
          #pragma unroll
          for (int d2 = 0; d2 < 4; ++d2) {
            const int kf = ((k0 + scol) >> 1) + d2;
            const float fr = __expf(-(float)kf * 0.07195578415606394f);
            const float ph = (float)row * fr;
            float s, c;
            __sincosf(ph, &s, &c);
            oa[d2 * 2]     = f2b(s);
            oa[d2 * 2 + 1] = f2b(c);
          }
        }
        *(u16x8*)&As[sidx] = oa;
      } else {
        f32x4 a0 = *(const f32x4*)&embf[(long)(m0 + row) * 256 + k0 + scol];
        f32x4 a1 = *(const f32x4*)&embf[(long)(m0 + row) * 256 + k0 + scol + 4];
        u16x8 oa = { f2b(a0[0]), f2b(a0[1]), f2b(a0[2]), f2b(a0[3]),
                     f2b(a1[0]), f2b(a1[1]), f2b(a1[2]), f2b(a1[3]) };
        *(u16x8*)&As[sidx] = oa;
      }
      f32x4 b0 = *(const f32x4*)&qkvf[(long)(n0 + row) * 256 + k0 + scol];
      f32x4 b1 = *(const f32x4*)&qkvf[(long)(n0 + row) * 256 + k0 + scol + 4];
      u16x8 ob = { f2b(b0[0]), f2b(b0[1]), f2b(b0[2]), f2b(b0[3]),
                   f2b(b1[0]), f2b(b1[1]), f2b(b1[2]), f2b(b1[3]) };
      *(u16x8*)&Bs[sidx] = ob;
    }
    __syncthreads();
    #pragma unroll
    for (int kk = 0; kk < 2; ++kk) {
      s16x8 a[4], bf[4];
      #pragma unroll
      for (int m = 0; m < 4; ++m) {
        const int ar = wr + m * 16 + lo;
        a[m] = *(const s16x8*)&As[ar * 64 + ((hi * 8 + kk * 32) ^ ((ar & 7) << 3))];
      }
      #pragma unroll
      for (int n = 0; n < 4; ++n) {
        const int br = wc + n * 16 + lo;
        bf[n] = *(const s16x8*)&Bs[br * 64 + ((hi * 8 + kk * 32) ^ ((br & 7) << 3))];
      }
      #pragma unroll
      for (int m = 0; m < 4; ++m)
        #pragma unroll
        for (int n = 0; n < 4; ++n)
          acc[m][n] = __builtin_amdgcn_mfma_f32_16x16x32_bf16(a[m], bf[n], acc[m][n], 0, 0, 0);
    }
  }
  #pragma unroll
  for (int m = 0; m < 4; ++m)
    #pragma unroll
    for (int n = 0; n < 4; ++n)
      #pragma unroll
      for (int r = 0; r < 4; ++r)
        C[(long)(m0 + wr + m * 16 + hi * 4 + r) * 6144 + n0 + wc + n * 16 + lo] = f2b(acc[m][n][r]);
}

// ---------------------------------------------------------------------------
// 64x64-tile bf16 MFMA GEMM (batched, f32 out) — fc split-K x8.
// ---------------------------------------------------------------------------
__global__ __launch_bounds__(256) void gemm_bf(
    const u16* __restrict__ A, int lda, long sA,
    const u16* __restrict__ B, int ldb, long sB,
    float* __restrict__ C, int ldc, long sC, int K)
{
  __shared__ __align__(16) u16 As[64 * 64];
  __shared__ __align__(16) u16 Bs[64 * 64];
  const int z = blockIdx.z;
  A += (long)z * sA;  B += (long)z * sB;
  const int m0 = blockIdx.y * 64, n0 = blockIdx.x * 64;
  const int tid = threadIdx.x;
  const int r8 = tid >> 3, s8t = (tid & 7) * 8;
  const int w = tid >> 6, l = tid & 63, hi = l >> 4, lo = l & 15;
  f32x4 acc[4] = {};
  for (int k0 = 0; k0 < K; k0 += 64) {
    __syncthreads();
    #pragma unroll
    for (int q = 0; q < 2; ++q) {
      const int row = q * 32 + r8;
      const int sidx = row * 64 + (s8t ^ ((row & 7) << 3));
      *(u16x8*)&As[sidx] = *(const u16x8*)&A[(long)(m0 + row) * lda + k0 + s8t];
      *(u16x8*)&Bs[sidx] = *(const u16x8*)&B[(long)(n0 + row) * ldb + k0 + s8t];
    }
    __syncthreads();
    #pragma unroll
    for (int kk = 0; kk < 2; ++kk) {
      const int arow = w * 16 + lo;
      s16x8 a = *(const s16x8*)&As[arow * 64 + ((hi * 8 + kk * 32) ^ ((arow & 7) << 3))];
      #pragma unroll
      for (int n = 0; n < 4; ++n) {
        const int brow = n * 16 + lo;
        s16x8 bfr = *(const s16x8*)&Bs[brow * 64 + ((hi * 8 + kk * 32) ^ ((brow & 7) << 3))];
        acc[n] = __builtin_amdgcn_mfma_f32_16x16x32_bf16(a, bfr, acc[n], 0, 0, 0);
      }
    }
  }
  const long zoff = (long)z * sC;
  #pragma unroll
  for (int n = 0; n < 4; ++n)
    #pragma unroll
    for (int r = 0; r < 4; ++r)
      C[zoff + (long)(m0 + w * 16 + hi * 4 + r) * ldc + n0 + n * 16 + lo] = acc[n][r];
}

// ---------------------------------------------------------------------------
// tables_kernel: merged cpqk (dual GEMM, blocks 0..127) + pqk (128..135) +
// pvfc (136..167). All 64x64 tiles, K=256, bf16 out.
// ---------------------------------------------------------------------------
__global__ __launch_bounds__(256) void tables_kernel(
    const u16* __restrict__ cqkv, const u16* __restrict__ pqkv,
    const u16* __restrict__ fcx,
    u16* __restrict__ cpqk, u16* __restrict__ pqk, u16* __restrict__ pvfc)
{
  __shared__ __align__(16) u16 As1[64 * 64], Bs1[64 * 64];
  __shared__ __align__(16) u16 As2[64 * 64], Bs2[64 * 64];
  const int blk = blockIdx.x;
  const u16 *A1, *A2 = nullptr, *B1, *B2 = nullptr;
  u16* C; int lda, ldb, ldc, m0; bool dual = false;
  if (blk < 128) {
    const int h = blk & 7, mt = blk >> 3;
    A1 = cqkv + h * 768 + 256; A2 = cqkv + h * 768;
    B1 = pqkv + h * 768;       B2 = pqkv + h * 768 + 256;
    lda = 6144; ldb = 6144; C = cpqk + (long)h * 65536; ldc = 64;
    m0 = mt * 64; dual = true;
  } else if (blk < 136) {
    const int h = blk - 128;
    A1 = pqkv + h * 768; B1 = pqkv + h * 768 + 256;
    lda = 6144; ldb = 6144; C = pqk + h * 4096; ldc = 64; m0 = 0;
  } else {
    const int idx = blk - 136, h = idx & 7, mt = idx >> 3;
    A1 = fcx + h * 256; B1 = pqkv + 512 + h * 768;
    lda = 2560; ldb = 6144; C = pvfc + h * 64; ldc = 2560; m0 = mt * 64;
  }
  const int tid = threadIdx.x;
  const int r8 = tid >> 3, s8t = (tid & 7) * 8;
  const int w = tid >> 6, l = tid & 63, hi = l >> 4, lo = l & 15;
  f32x4 acc[4] = {};
  for (int k0 = 0; k0 < 256; k0 += 64) {
    __syncthreads();
    #pragma unroll
    for (int q = 0; q < 2; ++q) {
      const int row = q * 32 + r8;
      const int sidx = row * 64 + (s8t ^ ((row & 7) << 3));
      *(u16x8*)&As1[sidx] = *(const u16x8*)&A1[(long)(m0 + row) * lda + k0 + s8t];
      *(u16x8*)&Bs1[sidx] = *(const u16x8*)&B1[(long)row * ldb + k0 + s8t];
      if (dual) {
        *(u16x8*)&As2[sidx] = *(const u16x8*)&A2[(long)(m0 + row) * lda + k0 + s8t];
        *(u16x8*)&Bs2[sidx] = *(const u16x8*)&B2[(long)row * ldb + k0 + s8t];
      }
    }
    __syncthreads();
    #pragma unroll
    for (int kk = 0; kk < 2; ++kk) {
      const int arow = w * 16 + lo;
      const int aidx = arow * 64 + ((hi * 8 + kk * 32) ^ ((arow & 7) << 3));
      s16x8 a1 = *(const s16x8*)&As1[aidx];
      #pragma unroll
      for (int n = 0; n < 4; ++n) {
        const int brow = n * 16 + lo;
        const int bidx = brow * 64 + ((hi * 8 + kk * 32) ^ ((brow & 7) << 3));
        acc[n] = __builtin_amdgcn_mfma_f32_16x16x32_bf16(a1, *(const s16x8*)&Bs1[bidx], acc[n], 0, 0, 0);
      }
      if (dual) {
        s16x8 a2 = *(const s16x8*)&As2[aidx];
        #pragma unroll
        for (int n = 0; n < 4; ++n) {
          const int brow = n * 16 + lo;
          const int bidx = brow * 64 + ((hi * 8 + kk * 32) ^ ((brow & 7) << 3));
          acc[n] = __builtin_amdgcn_mfma_f32_16x16x32_bf16(a2, *(const s16x8*)&Bs2[bidx], acc[n], 0, 0, 0);
        }
      }
    }
  }
  #pragma unroll
  for (int n = 0; n < 4; ++n)
    #pragma unroll
    for (int r = 0; r < 4; ++r)
      C[(long)(m0 + w * 16 + hi * 4 + r) * ldc + n * 16 + lo] = f2b(acc[n][r]);
}

// ---------------------------------------------------------------------------
// Attention per (h,b). blockIdx.x = h -> XCD affinity. 4 blocks/CU.
// R16 structure (proven 41.0 us) + setprio around QK MFMA only.
// ---------------------------------------------------------------------------
__global__ __launch_bounds__(256, 4) void attn_kernel(
    const int* __restrict__ cc, const u16* __restrict__ cqkv,
    const u16* __restrict__ cpqk, const u16* __restrict__ pqk,
    u16* __restrict__ outp)
{
  __shared__ __align__(16) u16 Ks[64 * 256];   // 32 KB: K -> tsum -> V -> pf
  __shared__ float poolp[4][64];
  __shared__ float pooled[64];
  const int h = blockIdx.x, b = blockIdx.y;
  const int tid = threadIdx.x;
  const long hq = (long)h * 768;

  const int w = tid >> 6, l = tid & 63, hi = l >> 4, lo = l & 15;
  const int r8 = tid >> 3, s8t = (tid & 7) * 8;
  const int rb = r8 + 32;
  const int swa = (r8 & 7) << 3, swb = (rb & 7) << 3;

  const int cl = cc[b * 64 + l];
  const float invn = 1.f / (float)__popcll(__ballot(cl != 0));

  const int ca = __shfl(cl, r8), cb2 = __shfl(cl, rb);
  const long rowa = (long)ca * 6144 + hq;
  const long rowb = (long)cb2 * 6144 + hq;

  // ---- all global loads issue here (128B/line per instr) ----
  u16x8 kr[8];
  #pragma unroll
  for (int p = 0; p < 4; ++p) {
    kr[p]     = *(const u16x8*)&cqkv[rowa + 256 + p * 64 + s8t];
    kr[p + 4] = *(const u16x8*)&cqkv[rowb + 256 + p * 64 + s8t];
  }
  u16x8 vr[8];
  #pragma unroll
  for (int p = 0; p < 4; ++p) {
    vr[p]     = *(const u16x8*)&cqkv[rowa + 512 + p * 64 + s8t];
    vr[p + 4] = *(const u16x8*)&cqkv[rowb + 512 + p * 64 + s8t];
  }
  u16x8 cta = *(const u16x8*)&cpqk[((long)h * 1024 + ca) * 64 + s8t];
  u16x8 ctb = *(const u16x8*)&cpqk[((long)h * 1024 + cb2) * 64 + s8t];
  u16x8 pta = *(const u16x8*)&pqk[(long)h * 4096 + (long)r8 * 64 + s8t];
  u16x8 ptb = *(const u16x8*)&pqk[(long)h * 4096 + (long)rb * 64 + s8t];
  const long qrow = (long)__shfl(cl, w * 16 + lo) * 6144 + hq;
  s16x8 a[8];
  #pragma unroll
  for (int kk = 0; kk < 8; ++kk)
    a[kk] = *(const s16x8*)&cqkv[qrow + kk * 32 + hi * 8];

  // ---- stage K into Ks (XOR-swizzled) ----
  #pragma unroll
  for (int p = 0; p < 4; ++p) {
    *(u16x8*)&Ks[r8 * 256 + ((p * 64 + s8t) ^ swa)] = kr[p];
    *(u16x8*)&Ks[rb * 256 + ((p * 64 + s8t) ^ swb)] = kr[p + 4];
  }
  __syncthreads();

  // ---- QK^T MFMA (setprio: 4 independent blocks/CU arbitrate) ----
  __builtin_amdgcn_s_setprio(1);
  f32x4 acc[4] = {};
  #pragma unroll
  for (int kk = 0; kk < 8; ++kk) {
    #pragma unroll
    for (int n = 0; n < 4; ++n) {
      const int brow = n * 16 + lo;
      s16x8 bfr = *(const s16x8*)&Ks[brow * 256 + ((hi * 8 + kk * 32) ^ ((brow & 7) << 3))];
      acc[n] = __builtin_amdgcn_mfma_f32_16x16x32_bf16(a[kk], bfr, acc[n], 0, 0, 0);
    }
  }
  __builtin_amdgcn_s_setprio(0);
  __syncthreads();   // K dead

  // ---- summed tables -> Ks u16[0:4096) (8 KB, bf16 — f32 spilled in R17) ----
  {
    u16x8 t0, t1;
    #pragma unroll
    for (int d = 0; d < 8; ++d) {
      t0[d] = f2b(b2f(cta[d]) + b2f(pta[d]));
      t1[d] = f2b(b2f(ctb[d]) + b2f(ptb[d]));
    }
    *(u16x8*)&Ks[r8 * 64 + (s8t ^ swa)] = t0;
    *(u16x8*)&Ks[rb * 64 + (s8t ^ swb)] = t1;
  }
  __syncthreads();

  // ---- softmax (tables from LDS; cs via shfl) ----
  const float scale = 0.0625f;
  int csj[4];
  #pragma unroll
  for (int n = 0; n < 4; ++n) csj[n] = __shfl(cl, n * 16 + lo);
  float ex[4][4];
  float wgt[4];
  #pragma unroll
  for (int r = 0; r < 4; ++r) {
    const int i = w * 16 + hi * 4 + r;
    const int tswz = (i & 7) << 3;
    float s[4];
    float mx = -3e38f;
    #pragma unroll
    for (int n = 0; n < 4; ++n) {
      const int j = n * 16 + lo;
      float v = (acc[n][r] + b2f(Ks[i * 64 + (j ^ tswz)])) * scale;
      if (csj[n] == 0) v = -1e9f;
      s[n] = v;
      mx = fmaxf(mx, v);
    }
    mx = fmaxf(mx, __shfl_xor(mx, 1));
    mx = fmaxf(mx, __shfl_xor(mx, 2));
    mx = fmaxf(mx, __shfl_xor(mx, 4));
    mx = fmaxf(mx, __shfl_xor(mx, 8));
    float sum = 0.f;
    #pragma unroll
    for (int n = 0; n < 4; ++n) { const float e = __expf(s[n] - mx); ex[n][r] = e; sum += e; }
    sum += __shfl_xor(sum, 1);
    sum += __shfl_xor(sum, 2);
    sum += __shfl_xor(sum, 4);
    sum += __shfl_xor(sum, 8);
    wgt[r] = (__shfl(cl, i) != 0 ? 1.f : 0.f) / sum;
  }
  #pragma unroll
  for (int n = 0; n < 4; ++n) {
    float cp = ex[n][0] * wgt[0] + ex[n][1] * wgt[1] + ex[n][2] * wgt[2] + ex[n][3] * wgt[3];
    cp += __shfl_xor(cp, 16);
    cp += __shfl_xor(cp, 32);
    if (hi == 0) poolp[w][n * 16 + lo] = cp;
  }
  __syncthreads();   // poolp ready; all table reads done -> Ks free

  // ---- pooled final (separate LDS) + raw cv staging ----
  if (tid < 64) {
    const float pl = (poolp[0][tid] + poolp[1][tid] + poolp[2][tid] + poolp[3][tid]) * invn;
    pooled[tid] = pl;
    outp[(long)b * 2560 + 2048 + h * 64 + tid] = f2b(pl);
  }
  #pragma unroll
  for (int p = 0; p < 4; ++p) {
    *(u16x8*)&Ks[r8 * 256 + ((p * 64 + s8t) ^ swa)] = vr[p];
    *(u16x8*)&Ks[rb * 256 + ((p * 64 + s8t) ^ swb)] = vr[p + 4];
  }
  __syncthreads();

  // ---- PV: blocked column-sum with pooled FMA ----
  const int g = tid >> 5, ch = tid & 31;
  float acc8[8] = {};
  #pragma unroll
  for (int jj = 0; jj < 8; ++jj) {
    const int j = g * 8 + jj;
    const float pj = pooled[j];
    u16x8 vv = *(const u16x8*)&Ks[j * 256 + ((ch * 8) ^ ((j & 7) << 3))];
    #pragma unroll
    for (int d = 0; d < 8; ++d) acc8[d] += pj * b2f(vv[d]);
  }
  #pragma unroll
  for (int d = 0; d < 8; ++d) acc8[d] += __shfl_xor(acc8[d], 32);
  __syncthreads();   // all V reads complete; Ks free for partials
  float* pfF = (float*)Ks;   // [4][256] f32 = 4 KB
  if (l < 32) {
    f32x4 lo4 = { acc8[0], acc8[1], acc8[2], acc8[3] };
    f32x4 hi4 = { acc8[4], acc8[5], acc8[6], acc8[7] };
    *(f32x4*)&pfF[w * 256 + ch * 8]     = lo4;
    *(f32x4*)&pfF[w * 256 + ch * 8 + 4] = hi4;
  }
  __syncthreads();
  const float o = pfF[tid] + pfF[256 + tid] + pfF[512 + tid] + pfF[768 + tid];
  outp[(long)b * 2560 + h * 256 + tid] = f2b(o);
}

// ---------------------------------------------------------------------------
// LN chain; input = 8 split-K partials of fc output + bias
// ---------------------------------------------------------------------------
__global__ __launch_bounds__(256) void ln_chain(
    const float* __restrict__ xp, const float* __restrict__ fcb,
    const float* __restrict__ g1, const float* __restrict__ b1,
    const float* __restrict__ g2, const float* __restrict__ b2,
    const float* __restrict__ g3, const float* __restrict__ b3,
    float* __restrict__ out)
{
  __shared__ float red[4];
  const int b = blockIdx.x, t = threadIdx.x;
  const long idx = (long)b * 256 + t;
  float v = fcb[t];
  #pragma unroll
  for (int z = 0; z < 8; ++z) v += xp[idx + (long)z * 131072];

  auto bsum = [&](float val) -> float {
    #pragma unroll
    for (int o = 32; o; o >>= 1) val += __shfl_down(val, o);
    __syncthreads();
    if ((t & 63) == 0) red[t >> 6] = val;
    __syncthreads();
    return red[0] + red[1] + red[2] + red[3];
  };

  float mean = bsum(v) * (1.f / 256.f);
  float d = v - mean;
  float var = bsum(d * d) * (1.f / 256.f);
  const float y1 = d * rsqrtf(var + 1e-5f) * g1[t] + b1[t];

  mean = bsum(y1) * (1.f / 256.f);
  d = y1 - mean;
  var = bsum(d * d) * (1.f / 256.f);
  const float y2 = d * rsqrtf(var + 1e-6f) * g2[t] + b2[t] + y1;

  mean = bsum(y2) * (1.f / 256.f);
  d = y2 - mean;
  var = bsum(d * d) * (1.f / 256.f);
  out[idx] = d * rsqrtf(var + 1e-5f) * g3[t] + b3[t];
}

// ---------------------------------------------------------------------------
extern "C" void kernel_launch(void* const* d_in, const int* in_sizes, int n_in,
                              void* d_out, int out_size, void* d_ws, size_t ws_size,
                              hipStream_t stream) {
  (void)in_sizes; (void)n_in; (void)out_size; (void)ws_size;
  const int*   cc    = (const int*)  d_in[0];
  const float* emb_w = (const float*)d_in[1];   // (1024,256)
  const float* qkv_w = (const float*)d_in[2];   // (6144,256)
  const float* fc_w  = (const float*)d_in[3];   // (256,2048)
  const float* fc_b  = (const float*)d_in[4];
  const float* sg    = (const float*)d_in[5];
  const float* sb    = (const float*)d_in[6];
  const float* fg    = (const float*)d_in[7];
  const float* fb    = (const float*)d_in[8];
  const float* bg    = (const float*)d_in[9];
  const float* bbv   = (const float*)d_in[10];
  float* out = (float*)d_out;

  char* p = (char*)d_ws;
  u16* fcx     = (u16*)p;  p += (size_t)256 * 2560 * 2;    // [fc_w | pvfc]
  u16* cqkv_bf = (u16*)p;  p += (size_t)1024 * 6144 * 2;
  u16* pqkv_bf = (u16*)p;  p += (size_t)128 * 6144 * 2;    // rows 64..127 zero
  u16* cpqk16  = (u16*)p;  p += (size_t)8 * 1024 * 64 * 2;
  u16* pqk16   = (u16*)p;  p += (size_t)8 * 64 * 64 * 2;
  u16* sdpa_bf = (u16*)p;  p += (size_t)512 * 2560 * 2;    // [attn-out | pooled]
  float* fco   = (float*)p; p += (size_t)8 * 512 * 256 * 4;

  // cqkv (y<8) + pqkv w/ in-register pe (y==8) + fc cast (y==9)
  gemm128<<<dim3(48, 10), dim3(256), 0, stream>>>(
      emb_w, qkv_w, fc_w, cqkv_bf, pqkv_bf, fcx);

  // merged cpqk + pqk + pvfc
  tables_kernel<<<dim3(168), dim3(256), 0, stream>>>(
      cqkv_bf, pqkv_bf, fcx, cpqk16, pqk16, fcx + 2048);

  // attention: blockIdx.x = h (XCD affinity), y = b
  attn_kernel<<<dim3(8, 512), dim3(256), 0, stream>>>(
      cc, cqkv_bf, cpqk16, pqk16, sdpa_bf);

  // fc split-K x8 over K=2560
  gemm_bf<<<dim3(4, 8, 8), dim3(256), 0, stream>>>(
      sdpa_bf, 2560, 320, fcx, 2560, 320, fco, 256, (long)512 * 256, 320);

  ln_chain<<<dim3(512), dim3(256), 0, stream>>>(fco, fc_b, sg, sb, fg, fb, bg, bbv, out);
}

// Round 19
// 76.905 us; speedup vs baseline: 1.0466x; 1.0452x over previous
//
#include <hip/hip_runtime.h>
#include <math.h>

typedef unsigned short u16;
typedef __attribute__((ext_vector_type(4))) float f32x4;
typedef __attribute__((ext_vector_type(8))) short s16x8;   // MFMA bf16 frag (8 bf16)
typedef __attribute__((ext_vector_type(4))) unsigned short u16x4;
typedef __attribute__((ext_vector_type(8))) unsigned short u16x8;

__device__ __forceinline__ u16 f2b(float f) {
  union { float f; unsigned u; } v; v.f = f;
  return (u16)((v.u + 0x7fffu + ((v.u >> 16) & 1u)) >> 16);
}
__device__ __forceinline__ float b2f(u16 b) {
  union { unsigned u; float f; } v; v.u = ((unsigned)b) << 16;
  return v.f;
}

// ---------------------------------------------------------------------------
// 128x128-tile bf16 MFMA GEMM with cast-in-staging (A,B sources are f32):
// y<8  -> cqkv = emb@qkv^T (1024x6144)
// y==8 -> pqkv = pe@qkv^T (128x6144); pe computed IN-REGISTER (sin/cos)
// y==9 -> fc_w f32 -> fcx bf16 cast only (48 blocks, strided)
// ---------------------------------------------------------------------------
__global__ __launch_bounds__(256) void gemm128(
    const float* __restrict__ embf, const float* __restrict__ qkvf,
    const float* __restrict__ fcf,
    u16* __restrict__ Ccq, u16* __restrict__ Cpq, u16* __restrict__ fcx)
{
  const int ytile = blockIdx.y;
  const int tid = threadIdx.x;
  if (ytile == 9) {
    for (int q = blockIdx.x * 256 + tid; q < 131072; q += 48 * 256) {
      const int off4 = q * 4;
      const int row = off4 >> 11, col = off4 & 2047;
      f32x4 v = *(const f32x4*)&fcf[(size_t)off4];
      u16x4 o = { f2b(v[0]), f2b(v[1]), f2b(v[2]), f2b(v[3]) };
      *(u16x4*)&fcx[(size_t)row * 2560 + col] = o;
    }
    return;
  }
  __shared__ __align__(16) u16 As[128 * 64];
  __shared__ __align__(16) u16 Bs[128 * 64];
  u16* C; int m0;
  const bool peA = (ytile == 8);
  if (peA) { C = Cpq; m0 = 0; }
  else     { C = Ccq; m0 = ytile * 128; }
  const int n0 = blockIdx.x * 128;
  const int w = tid >> 6, l = tid & 63, hi = l >> 4, lo = l & 15;
  const int wr = (w >> 1) * 64, wc = (w & 1) * 64;
  const int srow = tid >> 3, scol = (tid & 7) * 8;
  f32x4 acc[4][4] = {};
  for (int k0 = 0; k0 < 256; k0 += 64) {
    __syncthreads();
    #pragma unroll
    for (int q = 0; q < 4; ++q) {
      const int row = q * 32 + srow;
      const int sidx = row * 64 + (scol ^ ((row & 7) << 3));
      if (peA) {
        u16x8 oa = {0, 0, 0, 0, 0, 0, 0, 0};
        if (row < 64) {
          #pragma unroll
          for (int d2 = 0; d2 < 4; ++d2) {
            const int kf = ((k0 + scol) >> 1) + d2;
            const float fr = __expf(-(float)kf * 0.07195578415606394f);
            const float ph = (float)row * fr;
            float s, c;
            __sincosf(ph, &s, &c);
            oa[d2 * 2]     = f2b(s);
            oa[d2 * 2 + 1] = f2b(c);
          }
        }
        *(u16x8*)&As[sidx] = oa;
      } else {
        f32x4 a0 = *(const f32x4*)&embf[(long)(m0 + row) * 256 + k0 + scol];
        f32x4 a1 = *(const f32x4*)&embf[(long)(m0 + row) * 256 + k0 + scol + 4];
        u16x8 oa = { f2b(a0[0]), f2b(a0[1]), f2b(a0[2]), f2b(a0[3]),
                     f2b(a1[0]), f2b(a1[1]), f2b(a1[2]), f2b(a1[3]) };
        *(u16x8*)&As[sidx] = oa;
      }
      f32x4 b0 = *(const f32x4*)&qkvf[(long)(n0 + row) * 256 + k0 + scol];
      f32x4 b1 = *(const f32x4*)&qkvf[(long)(n0 + row) * 256 + k0 + scol + 4];
      u16x8 ob = { f2b(b0[0]), f2b(b0[1]), f2b(b0[2]), f2b(b0[3]),
                   f2b(b1[0]), f2b(b1[1]), f2b(b1[2]), f2b(b1[3]) };
      *(u16x8*)&Bs[sidx] = ob;
    }
    __syncthreads();
    #pragma unroll
    for (int kk = 0; kk < 2; ++kk) {
      s16x8 a[4], bf[4];
      #pragma unroll
      for (int m = 0; m < 4; ++m) {
        const int ar = wr + m * 16 + lo;
        a[m] = *(const s16x8*)&As[ar * 64 + ((hi * 8 + kk * 32) ^ ((ar & 7) << 3))];
      }
      #pragma unroll
      for (int n = 0; n < 4; ++n) {
        const int br = wc + n * 16 + lo;
        bf[n] = *(const s16x8*)&Bs[br * 64 + ((hi * 8 + kk * 32) ^ ((br & 7) << 3))];
      }
      #pragma unroll
      for (int m = 0; m < 4; ++m)
        #pragma unroll
        for (int n = 0; n < 4; ++n)
          acc[m][n] = __builtin_amdgcn_mfma_f32_16x16x32_bf16(a[m], bf[n], acc[m][n], 0, 0, 0);
    }
  }
  #pragma unroll
  for (int m = 0; m < 4; ++m)
    #pragma unroll
    for (int n = 0; n < 4; ++n)
      #pragma unroll
      for (int r = 0; r < 4; ++r)
        C[(long)(m0 + wr + m * 16 + hi * 4 + r) * 6144 + n0 + wc + n * 16 + lo] = f2b(acc[m][n][r]);
}

// ---------------------------------------------------------------------------
// 64x64-tile bf16 MFMA GEMM (batched, f32 out) — fc split-K x8.
// ---------------------------------------------------------------------------
__global__ __launch_bounds__(256) void gemm_bf(
    const u16* __restrict__ A, int lda, long sA,
    const u16* __restrict__ B, int ldb, long sB,
    float* __restrict__ C, int ldc, long sC, int K)
{
  __shared__ __align__(16) u16 As[64 * 64];
  __shared__ __align__(16) u16 Bs[64 * 64];
  const int z = blockIdx.z;
  A += (long)z * sA;  B += (long)z * sB;
  const int m0 = blockIdx.y * 64, n0 = blockIdx.x * 64;
  const int tid = threadIdx.x;
  const int r8 = tid >> 3, s8t = (tid & 7) * 8;
  const int w = tid >> 6, l = tid & 63, hi = l >> 4, lo = l & 15;
  f32x4 acc[4] = {};
  for (int k0 = 0; k0 < K; k0 += 64) {
    __syncthreads();
    #pragma unroll
    for (int q = 0; q < 2; ++q) {
      const int row = q * 32 + r8;
      const int sidx = row * 64 + (s8t ^ ((row & 7) << 3));
      *(u16x8*)&As[sidx] = *(const u16x8*)&A[(long)(m0 + row) * lda + k0 + s8t];
      *(u16x8*)&Bs[sidx] = *(const u16x8*)&B[(long)(n0 + row) * ldb + k0 + s8t];
    }
    __syncthreads();
    #pragma unroll
    for (int kk = 0; kk < 2; ++kk) {
      const int arow = w * 16 + lo;
      s16x8 a = *(const s16x8*)&As[arow * 64 + ((hi * 8 + kk * 32) ^ ((arow & 7) << 3))];
      #pragma unroll
      for (int n = 0; n < 4; ++n) {
        const int brow = n * 16 + lo;
        s16x8 bfr = *(const s16x8*)&Bs[brow * 64 + ((hi * 8 + kk * 32) ^ ((brow & 7) << 3))];
        acc[n] = __builtin_amdgcn_mfma_f32_16x16x32_bf16(a, bfr, acc[n], 0, 0, 0);
      }
    }
  }
  const long zoff = (long)z * sC;
  #pragma unroll
  for (int n = 0; n < 4; ++n)
    #pragma unroll
    for (int r = 0; r < 4; ++r)
      C[zoff + (long)(m0 + w * 16 + hi * 4 + r) * ldc + n0 + n * 16 + lo] = acc[n][r];
}

// ---------------------------------------------------------------------------
// tables_kernel: merged cpqk (dual GEMM, blocks 0..127) + pqk (128..135) +
// pvfc (136..167). All 64x64 tiles, K=256, bf16 out.
// ---------------------------------------------------------------------------
__global__ __launch_bounds__(256) void tables_kernel(
    const u16* __restrict__ cqkv, const u16* __restrict__ pqkv,
    const u16* __restrict__ fcx,
    u16* __restrict__ cpqk, u16* __restrict__ pqk, u16* __restrict__ pvfc)
{
  __shared__ __align__(16) u16 As1[64 * 64], Bs1[64 * 64];
  __shared__ __align__(16) u16 As2[64 * 64], Bs2[64 * 64];
  const int blk = blockIdx.x;
  const u16 *A1, *A2 = nullptr, *B1, *B2 = nullptr;
  u16* C; int lda, ldb, ldc, m0; bool dual = false;
  if (blk < 128) {
    const int h = blk & 7, mt = blk >> 3;
    A1 = cqkv + h * 768 + 256; A2 = cqkv + h * 768;
    B1 = pqkv + h * 768;       B2 = pqkv + h * 768 + 256;
    lda = 6144; ldb = 6144; C = cpqk + (long)h * 65536; ldc = 64;
    m0 = mt * 64; dual = true;
  } else if (blk < 136) {
    const int h = blk - 128;
    A1 = pqkv + h * 768; B1 = pqkv + h * 768 + 256;
    lda = 6144; ldb = 6144; C = pqk + h * 4096; ldc = 64; m0 = 0;
  } else {
    const int idx = blk - 136, h = idx & 7, mt = idx >> 3;
    A1 = fcx + h * 256; B1 = pqkv + 512 + h * 768;
    lda = 2560; ldb = 6144; C = pvfc + h * 64; ldc = 2560; m0 = mt * 64;
  }
  const int tid = threadIdx.x;
  const int r8 = tid >> 3, s8t = (tid & 7) * 8;
  const int w = tid >> 6, l = tid & 63, hi = l >> 4, lo = l & 15;
  f32x4 acc[4] = {};
  for (int k0 = 0; k0 < 256; k0 += 64) {
    __syncthreads();
    #pragma unroll
    for (int q = 0; q < 2; ++q) {
      const int row = q * 32 + r8;
      const int sidx = row * 64 + (s8t ^ ((row & 7) << 3));
      *(u16x8*)&As1[sidx] = *(const u16x8*)&A1[(long)(m0 + row) * lda + k0 + s8t];
      *(u16x8*)&Bs1[sidx] = *(const u16x8*)&B1[(long)row * ldb + k0 + s8t];
      if (dual) {
        *(u16x8*)&As2[sidx] = *(const u16x8*)&A2[(long)(m0 + row) * lda + k0 + s8t];
        *(u16x8*)&Bs2[sidx] = *(const u16x8*)&B2[(long)row * ldb + k0 + s8t];
      }
    }
    __syncthreads();
    #pragma unroll
    for (int kk = 0; kk < 2; ++kk) {
      const int arow = w * 16 + lo;
      const int aidx = arow * 64 + ((hi * 8 + kk * 32) ^ ((arow & 7) << 3));
      s16x8 a1 = *(const s16x8*)&As1[aidx];
      #pragma unroll
      for (int n = 0; n < 4; ++n) {
        const int brow = n * 16 + lo;
        const int bidx = brow * 64 + ((hi * 8 + kk * 32) ^ ((brow & 7) << 3));
        acc[n] = __builtin_amdgcn_mfma_f32_16x16x32_bf16(a1, *(const s16x8*)&Bs1[bidx], acc[n], 0, 0, 0);
      }
      if (dual) {
        s16x8 a2 = *(const s16x8*)&As2[aidx];
        #pragma unroll
        for (int n = 0; n < 4; ++n) {
          const int brow = n * 16 + lo;
          const int bidx = brow * 64 + ((hi * 8 + kk * 32) ^ ((brow & 7) << 3));
          acc[n] = __builtin_amdgcn_mfma_f32_16x16x32_bf16(a2, *(const s16x8*)&Bs2[bidx], acc[n], 0, 0, 0);
        }
      }
    }
  }
  #pragma unroll
  for (int n = 0; n < 4; ++n)
    #pragma unroll
    for (int r = 0; r < 4; ++r)
      C[(long)(m0 + w * 16 + hi * 4 + r) * ldc + n * 16 + lo] = f2b(acc[n][r]);
}

// ---------------------------------------------------------------------------
// Attention per (h,b). blockIdx.x = h -> XCD affinity. 4 blocks/CU.
// Exact R16 structure (77.06 us total): raw cv staging, blocked vector PV
// with pooled FMA, bf16 tables, NO setprio (R18: sched fence -> spill).
// ---------------------------------------------------------------------------
__global__ __launch_bounds__(256, 4) void attn_kernel(
    const int* __restrict__ cc, const u16* __restrict__ cqkv,
    const u16* __restrict__ cpqk, const u16* __restrict__ pqk,
    u16* __restrict__ outp)
{
  __shared__ __align__(16) u16 Ks[64 * 256];   // 32 KB: K -> tsum -> V -> pf
  __shared__ float poolp[4][64];
  __shared__ float pooled[64];
  const int h = blockIdx.x, b = blockIdx.y;
  const int tid = threadIdx.x;
  const long hq = (long)h * 768;

  const int w = tid >> 6, l = tid & 63, hi = l >> 4, lo = l & 15;
  const int r8 = tid >> 3, s8t = (tid & 7) * 8;
  const int rb = r8 + 32;
  const int swa = (r8 & 7) << 3, swb = (rb & 7) << 3;

  const int cl = cc[b * 64 + l];
  const float invn = 1.f / (float)__popcll(__ballot(cl != 0));

  const int ca = __shfl(cl, r8), cb2 = __shfl(cl, rb);
  const long rowa = (long)ca * 6144 + hq;
  const long rowb = (long)cb2 * 6144 + hq;

  // ---- all global loads issue here (128B/line per instr) ----
  u16x8 kr[8];
  #pragma unroll
  for (int p = 0; p < 4; ++p) {
    kr[p]     = *(const u16x8*)&cqkv[rowa + 256 + p * 64 + s8t];
    kr[p + 4] = *(const u16x8*)&cqkv[rowb + 256 + p * 64 + s8t];
  }
  u16x8 vr[8];
  #pragma unroll
  for (int p = 0; p < 4; ++p) {
    vr[p]     = *(const u16x8*)&cqkv[rowa + 512 + p * 64 + s8t];
    vr[p + 4] = *(const u16x8*)&cqkv[rowb + 512 + p * 64 + s8t];
  }
  u16x8 cta = *(const u16x8*)&cpqk[((long)h * 1024 + ca) * 64 + s8t];
  u16x8 ctb = *(const u16x8*)&cpqk[((long)h * 1024 + cb2) * 64 + s8t];
  u16x8 pta = *(const u16x8*)&pqk[(long)h * 4096 + (long)r8 * 64 + s8t];
  u16x8 ptb = *(const u16x8*)&pqk[(long)h * 4096 + (long)rb * 64 + s8t];
  const long qrow = (long)__shfl(cl, w * 16 + lo) * 6144 + hq;
  s16x8 a[8];
  #pragma unroll
  for (int kk = 0; kk < 8; ++kk)
    a[kk] = *(const s16x8*)&cqkv[qrow + kk * 32 + hi * 8];

  // ---- stage K into Ks (XOR-swizzled) ----
  #pragma unroll
  for (int p = 0; p < 4; ++p) {
    *(u16x8*)&Ks[r8 * 256 + ((p * 64 + s8t) ^ swa)] = kr[p];
    *(u16x8*)&Ks[rb * 256 + ((p * 64 + s8t) ^ swb)] = kr[p + 4];
  }
  __syncthreads();

  // ---- QK^T MFMA ----
  f32x4 acc[4] = {};
  #pragma unroll
  for (int kk = 0; kk < 8; ++kk) {
    #pragma unroll
    for (int n = 0; n < 4; ++n) {
      const int brow = n * 16 + lo;
      s16x8 bfr = *(const s16x8*)&Ks[brow * 256 + ((hi * 8 + kk * 32) ^ ((brow & 7) << 3))];
      acc[n] = __builtin_amdgcn_mfma_f32_16x16x32_bf16(a[kk], bfr, acc[n], 0, 0, 0);
    }
  }
  __syncthreads();   // K dead

  // ---- summed tables -> Ks u16[0:4096) (8 KB) ----
  {
    u16x8 t0, t1;
    #pragma unroll
    for (int d = 0; d < 8; ++d) {
      t0[d] = f2b(b2f(cta[d]) + b2f(pta[d]));
      t1[d] = f2b(b2f(ctb[d]) + b2f(ptb[d]));
    }
    *(u16x8*)&Ks[r8 * 64 + (s8t ^ swa)] = t0;
    *(u16x8*)&Ks[rb * 64 + (s8t ^ swb)] = t1;
  }
  __syncthreads();

  // ---- softmax (tables from LDS; cs via shfl) ----
  const float scale = 0.0625f;
  int csj[4];
  #pragma unroll
  for (int n = 0; n < 4; ++n) csj[n] = __shfl(cl, n * 16 + lo);
  float ex[4][4];
  float wgt[4];
  #pragma unroll
  for (int r = 0; r < 4; ++r) {
    const int i = w * 16 + hi * 4 + r;
    const int tswz = (i & 7) << 3;
    float s[4];
    float mx = -3e38f;
    #pragma unroll
    for (int n = 0; n < 4; ++n) {
      const int j = n * 16 + lo;
      float v = (acc[n][r] + b2f(Ks[i * 64 + (j ^ tswz)])) * scale;
      if (csj[n] == 0) v = -1e9f;
      s[n] = v;
      mx = fmaxf(mx, v);
    }
    mx = fmaxf(mx, __shfl_xor(mx, 1));
    mx = fmaxf(mx, __shfl_xor(mx, 2));
    mx = fmaxf(mx, __shfl_xor(mx, 4));
    mx = fmaxf(mx, __shfl_xor(mx, 8));
    float sum = 0.f;
    #pragma unroll
    for (int n = 0; n < 4; ++n) { const float e = __expf(s[n] - mx); ex[n][r] = e; sum += e; }
    sum += __shfl_xor(sum, 1);
    sum += __shfl_xor(sum, 2);
    sum += __shfl_xor(sum, 4);
    sum += __shfl_xor(sum, 8);
    wgt[r] = (__shfl(cl, i) != 0 ? 1.f : 0.f) / sum;
  }
  #pragma unroll
  for (int n = 0; n < 4; ++n) {
    float cp = ex[n][0] * wgt[0] + ex[n][1] * wgt[1] + ex[n][2] * wgt[2] + ex[n][3] * wgt[3];
    cp += __shfl_xor(cp, 16);
    cp += __shfl_xor(cp, 32);
    if (hi == 0) poolp[w][n * 16 + lo] = cp;
  }
  __syncthreads();   // poolp ready; all table reads done -> Ks free

  // ---- pooled final (separate LDS) + raw cv staging ----
  if (tid < 64) {
    const float pl = (poolp[0][tid] + poolp[1][tid] + poolp[2][tid] + poolp[3][tid]) * invn;
    pooled[tid] = pl;
    outp[(long)b * 2560 + 2048 + h * 64 + tid] = f2b(pl);
  }
  #pragma unroll
  for (int p = 0; p < 4; ++p) {
    *(u16x8*)&Ks[r8 * 256 + ((p * 64 + s8t) ^ swa)] = vr[p];
    *(u16x8*)&Ks[rb * 256 + ((p * 64 + s8t) ^ swb)] = vr[p + 4];
  }
  __syncthreads();

  // ---- PV: blocked column-sum with pooled FMA ----
  const int g = tid >> 5, ch = tid & 31;
  float acc8[8] = {};
  #pragma unroll
  for (int jj = 0; jj < 8; ++jj) {
    const int j = g * 8 + jj;
    const float pj = pooled[j];
    u16x8 vv = *(const u16x8*)&Ks[j * 256 + ((ch * 8) ^ ((j & 7) << 3))];
    #pragma unroll
    for (int d = 0; d < 8; ++d) acc8[d] += pj * b2f(vv[d]);
  }
  #pragma unroll
  for (int d = 0; d < 8; ++d) acc8[d] += __shfl_xor(acc8[d], 32);
  __syncthreads();   // all V reads complete; Ks free for partials
  float* pfF = (float*)Ks;   // [4][256] f32 = 4 KB
  if (l < 32) {
    f32x4 lo4 = { acc8[0], acc8[1], acc8[2], acc8[3] };
    f32x4 hi4 = { acc8[4], acc8[5], acc8[6], acc8[7] };
    *(f32x4*)&pfF[w * 256 + ch * 8]     = lo4;
    *(f32x4*)&pfF[w * 256 + ch * 8 + 4] = hi4;
  }
  __syncthreads();
  const float o = pfF[tid] + pfF[256 + tid] + pfF[512 + tid] + pfF[768 + tid];
  outp[(long)b * 2560 + h * 256 + tid] = f2b(o);
}

// ---------------------------------------------------------------------------
// LN chain; input = 8 split-K partials of fc output + bias
// ---------------------------------------------------------------------------
__global__ __launch_bounds__(256) void ln_chain(
    const float* __restrict__ xp, const float* __restrict__ fcb,
    const float* __restrict__ g1, const float* __restrict__ b1,
    const float* __restrict__ g2, const float* __restrict__ b2,
    const float* __restrict__ g3, const float* __restrict__ b3,
    float* __restrict__ out)
{
  __shared__ float red[4];
  const int b = blockIdx.x, t = threadIdx.x;
  const long idx = (long)b * 256 + t;
  float v = fcb[t];
  #pragma unroll
  for (int z = 0; z < 8; ++z) v += xp[idx + (long)z * 131072];

  auto bsum = [&](float val) -> float {
    #pragma unroll
    for (int o = 32; o; o >>= 1) val += __shfl_down(val, o);
    __syncthreads();
    if ((t & 63) == 0) red[t >> 6] = val;
    __syncthreads();
    return red[0] + red[1] + red[2] + red[3];
  };

  float mean = bsum(v) * (1.f / 256.f);
  float d = v - mean;
  float var = bsum(d * d) * (1.f / 256.f);
  const float y1 = d * rsqrtf(var + 1e-5f) * g1[t] + b1[t];

  mean = bsum(y1) * (1.f / 256.f);
  d = y1 - mean;
  var = bsum(d * d) * (1.f / 256.f);
  const float y2 = d * rsqrtf(var + 1e-6f) * g2[t] + b2[t] + y1;

  mean = bsum(y2) * (1.f / 256.f);
  d = y2 - mean;
  var = bsum(d * d) * (1.f / 256.f);
  out[idx] = d * rsqrtf(var + 1e-5f) * g3[t] + b3[t];
}

// ---------------------------------------------------------------------------
extern "C" void kernel_launch(void* const* d_in, const int* in_sizes, int n_in,
                              void* d_out, int out_size, void* d_ws, size_t ws_size,
                              hipStream_t stream) {
  (void)in_sizes; (void)n_in; (void)out_size; (void)ws_size;
  const int*   cc    = (const int*)  d_in[0];
  const float* emb_w = (const float*)d_in[1];   // (1024,256)
  const float* qkv_w = (const float*)d_in[2];   // (6144,256)
  const float* fc_w  = (const float*)d_in[3];   // (256,2048)
  const float* fc_b  = (const float*)d_in[4];
  const float* sg    = (const float*)d_in[5];
  const float* sb    = (const float*)d_in[6];
  const float* fg    = (const float*)d_in[7];
  const float* fb    = (const float*)d_in[8];
  const float* bg    = (const float*)d_in[9];
  const float* bbv   = (const float*)d_in[10];
  float* out = (float*)d_out;

  char* p = (char*)d_ws;
  u16* fcx     = (u16*)p;  p += (size_t)256 * 2560 * 2;    // [fc_w | pvfc]
  u16* cqkv_bf = (u16*)p;  p += (size_t)1024 * 6144 * 2;
  u16* pqkv_bf = (u16*)p;  p += (size_t)128 * 6144 * 2;    // rows 64..127 zero
  u16* cpqk16  = (u16*)p;  p += (size_t)8 * 1024 * 64 * 2;
  u16* pqk16   = (u16*)p;  p += (size_t)8 * 64 * 64 * 2;
  u16* sdpa_bf = (u16*)p;  p += (size_t)512 * 2560 * 2;    // [attn-out | pooled]
  float* fco   = (float*)p; p += (size_t)8 * 512 * 256 * 4;

  // cqkv (y<8) + pqkv w/ in-register pe (y==8) + fc cast (y==9)
  gemm128<<<dim3(48, 10), dim3(256), 0, stream>>>(
      emb_w, qkv_w, fc_w, cqkv_bf, pqkv_bf, fcx);

  // merged cpqk + pqk + pvfc
  tables_kernel<<<dim3(168), dim3(256), 0, stream>>>(
      cqkv_bf, pqkv_bf, fcx, cpqk16, pqk16, fcx + 2048);

  // attention: blockIdx.x = h (XCD affinity), y = b
  attn_kernel<<<dim3(8, 512), dim3(256), 0, stream>>>(
      cc, cqkv_bf, cpqk16, pqk16, sdpa_bf);

  // fc split-K x8 over K=2560
  gemm_bf<<<dim3(4, 8, 8), dim3(256), 0, stream>>>(
      sdpa_bf, 2560, 320, fcx, 2560, 320, fco, 256, (long)512 * 256, 320);

  ln_chain<<<dim3(512), dim3(256), 0, stream>>>(fco, fc_b, sg, sb, fg, fb, bg, bbv, out);
}